// Round 7
// baseline (113.655 us; speedup 1.0000x reference)
//
#include <hip/hip_runtime.h>
#include <math.h>

// GLIF forward, two-kernel version (R5 structure + compile-time T unroll):
//  K1 (prep): iscale[t][c] = 1 - be_c*(1 - sigmoid(conduct[t][c])) (64KB)
//             + per-channel derived params (20KB) into d_ws.
//  K2 (fwd):  scan over T; ONE batch row (4 channels) per thread — small
//             VGPR footprint, max occupancy. T=16 template: static prefetch
//             guards + immediate address offsets. Depth-2 NT prefetch on x,
//             depth-1 on iscale, plain stores on out.

typedef float f32x4 __attribute__((ext_vector_type(4)));

__device__ __forceinline__ float sigmoidf_acc(float v) {
    return 1.0f / (1.0f + expf(-v));
}

__global__ __launch_bounds__(256) void glif_prep_kernel(
    const float* __restrict__ conduct,
    const float* __restrict__ beta,
    const float* __restrict__ tau,
    const float* __restrict__ Vth,
    const float* __restrict__ leak,
    const float* __restrict__ reVth,
    const float* __restrict__ alpha,
    const float* __restrict__ gamma_,
    float* __restrict__ ws,      // [T*C] iscale, then 5 x [C] params
    int TC4, int C4)
{
#pragma clang fp contract(off)
    int idx = blockIdx.x * blockDim.x + threadIdx.x;
    if (idx >= TC4) return;
    int c4 = idx & (C4 - 1);

    const f32x4 bev = reinterpret_cast<const f32x4*>(beta)[c4];
    const f32x4 cv  = reinterpret_cast<const f32x4*>(conduct)[idx];
    f32x4 ov;
    #pragma unroll
    for (int j = 0; j < 4; ++j) {
        float be = bev[j] > 0.0f ? 1.0f : 0.0f;
        float ct = sigmoidf_acc(cv[j]);
        ov[j] = 1.0f - be * (1.0f - ct);   // exact ref expression order
    }
    reinterpret_cast<f32x4*>(ws)[idx] = ov;

    if (idx < C4) {
        const int TC = TC4 * 4;
        const f32x4 alv = reinterpret_cast<const f32x4*>(alpha)[c4];
        const f32x4 gav = reinterpret_cast<const f32x4*>(gamma_)[c4];
        const f32x4 tav = reinterpret_cast<const f32x4*>(tau  )[c4];
        const f32x4 vtv = reinterpret_cast<const f32x4*>(Vth  )[c4];
        const f32x4 lkv = reinterpret_cast<const f32x4*>(leak )[c4];
        const f32x4 rvv = reinterpret_cast<const f32x4*>(reVth)[c4];

        f32x4 decay, leakt, vth_s, rvc, ga;
        #pragma unroll
        for (int j = 0; j < 4; ++j) {
            float al = alv[j] > 0.0f ? 1.0f : 0.0f;
            float g  = gav[j] > 0.0f ? 1.0f : 0.0f;
            float tau_s   = sigmoidf_acc(tav[j]);
            float vth_sj  = sigmoidf_acc(vtv[j]);
            float leak_s  = sigmoidf_acc(lkv[j]);
            float reVth_s = sigmoidf_acc(rvv[j]);
            decay[j] = 1.0f - al * (1.0f - tau_s);
            leakt[j] = (1.0f - al) * leak_s;
            vth_s[j] = vth_sj;
            rvc[j]   = (1.0f - g) * reVth_s;
            ga[j]    = g;
        }
        f32x4* p = reinterpret_cast<f32x4*>(ws + TC);
        p[0 * C4 + c4] = decay;
        p[1 * C4 + c4] = leakt;
        p[2 * C4 + c4] = vth_s;
        p[3 * C4 + c4] = rvc;
        p[4 * C4 + c4] = ga;
    }
}

template<int TT>
__global__ __launch_bounds__(256) void glif_fwd_kernel(
    const float* __restrict__ x,
    const float* __restrict__ ws,   // iscale [T*C] + params 5x[C]
    float* __restrict__ out,
    int BC4, int C4, int Trt)
{
#pragma clang fp contract(off)
    const int T = (TT > 0) ? TT : Trt;
    int idx = blockIdx.x * blockDim.x + threadIdx.x;
    if (idx >= BC4) return;
    int c4 = idx & (C4 - 1);
    const int TC4 = T * C4;

    const f32x4* __restrict__ p = reinterpret_cast<const f32x4*>(ws) + TC4;
    const f32x4 decay = p[0 * C4 + c4];
    const f32x4 leakt = p[1 * C4 + c4];
    const f32x4 vth_s = p[2 * C4 + c4];
    const f32x4 rvc   = p[3 * C4 + c4];
    const f32x4 ga    = p[4 * C4 + c4];

    float u[4] = {0.0f, 0.0f, 0.0f, 0.0f};
    float o[4] = {0.0f, 0.0f, 0.0f, 0.0f};

    const f32x4* __restrict__ x4  = reinterpret_cast<const f32x4*>(x);
    const f32x4* __restrict__ is4 = reinterpret_cast<const f32x4*>(ws);
    f32x4* __restrict__ o4 = reinterpret_cast<f32x4*>(out);

    const size_t base = (size_t)idx;
    const size_t strd = (size_t)BC4;

    // ---- software pipeline: depth-2 on x, depth-1 on iscale ----
    f32x4 xp0 = __builtin_nontemporal_load(&x4[base]);              // t = 0
    f32x4 xp1;
    if (T > 1) xp1 = __builtin_nontemporal_load(&x4[base + strd]);  // t = 1
    f32x4 ivc = is4[c4];                                            // t = 0

    #pragma unroll
    for (int t = 0; t < T; ++t) {
        f32x4 xp2;
        if (t + 2 < T)
            xp2 = __builtin_nontemporal_load(&x4[base + (size_t)(t + 2) * strd]);
        f32x4 ivn = ivc;
        if (t + 1 < T)
            ivn = is4[(size_t)(t + 1) * (size_t)C4 + (size_t)c4];

        f32x4 ov;
        #pragma unroll
        for (int j = 0; j < 4; ++j) {
            float I  = xp0[j] * ivc[j];
            float un = decay[j] * u[j] * (1.0f - ga[j] * o[j]) - leakt[j] + I
                       - rvc[j] * o[j];
            float on = (un - vth_s[j] >= 0.0f) ? 1.0f : 0.0f;
            u[j] = un;
            o[j] = on;
            ov[j] = on;
        }

        o4[base + (size_t)t * strd] = ov;   // plain store

        xp0 = xp1;
        xp1 = xp2;
        ivc = ivn;
    }
}

extern "C" void kernel_launch(void* const* d_in, const int* in_sizes, int n_in,
                              void* d_out, int out_size, void* d_ws, size_t ws_size,
                              hipStream_t stream) {
    const float* x       = (const float*)d_in[0];
    const float* tau     = (const float*)d_in[1];
    const float* Vth     = (const float*)d_in[2];
    const float* leak    = (const float*)d_in[3];
    const float* reVth   = (const float*)d_in[4];
    const float* conduct = (const float*)d_in[5];
    const float* alpha   = (const float*)d_in[6];
    const float* beta    = (const float*)d_in[7];
    const float* gamma_  = (const float*)d_in[8];
    float* out = (float*)d_out;

    const int C  = in_sizes[1];                        // 1024
    const int T  = in_sizes[5] / C;                    // 16
    const long long BC = (long long)in_sizes[0] / T;   // B*C
    const int BC4 = (int)(BC / 4);
    const int C4  = C / 4;
    const int TC4 = T * C4;

    const int block = 256;

    float* ws = (float*)d_ws;  // needs (T*C + 5*C)*4 = 84KB
    glif_prep_kernel<<<(TC4 + block - 1) / block, block, 0, stream>>>(
        conduct, beta, tau, Vth, leak, reVth, alpha, gamma_, ws, TC4, C4);

    if (T == 16) {
        glif_fwd_kernel<16><<<(BC4 + block - 1) / block, block, 0, stream>>>(
            x, ws, out, BC4, C4, T);
    } else {
        glif_fwd_kernel<0><<<(BC4 + block - 1) / block, block, 0, stream>>>(
            x, ws, out, BC4, C4, T);
    }
}

// Round 8
// 101.136 us; speedup vs baseline: 1.1238x; 1.1238x over previous
//
#include <hip/hip_runtime.h>
#include <math.h>

// GLIF forward, two-kernel version (R5 structure + 2 rows/thread, ROLLED loop):
//  K1 (prep): iscale[t][c] = 1 - be_c*(1 - sigmoid(conduct[t][c])) (64KB)
//             + per-channel derived params (20KB) into d_ws.
//  K2 (fwd):  rolled runtime-T scan. Each thread owns 4 channels of TWO
//             batch rows (r, r+B/2): shared params, 2 independent u-chains,
//             2KB read + 2KB write per wave per t-step. Depth-2 NT prefetch
//             on each x stream; iscale loaded directly (L1/L2-hot);
//             plain stores. NO unroll (R7 showed full unroll costs +12us).

typedef float f32x4 __attribute__((ext_vector_type(4)));

__device__ __forceinline__ float sigmoidf_acc(float v) {
    return 1.0f / (1.0f + expf(-v));
}

__global__ __launch_bounds__(256) void glif_prep_kernel(
    const float* __restrict__ conduct,
    const float* __restrict__ beta,
    const float* __restrict__ tau,
    const float* __restrict__ Vth,
    const float* __restrict__ leak,
    const float* __restrict__ reVth,
    const float* __restrict__ alpha,
    const float* __restrict__ gamma_,
    float* __restrict__ ws,      // [T*C] iscale, then 5 x [C] params
    int TC4, int C4)
{
#pragma clang fp contract(off)
    int idx = blockIdx.x * blockDim.x + threadIdx.x;
    if (idx >= TC4) return;
    int c4 = idx & (C4 - 1);

    const f32x4 bev = reinterpret_cast<const f32x4*>(beta)[c4];
    const f32x4 cv  = reinterpret_cast<const f32x4*>(conduct)[idx];
    f32x4 ov;
    #pragma unroll
    for (int j = 0; j < 4; ++j) {
        float be = bev[j] > 0.0f ? 1.0f : 0.0f;
        float ct = sigmoidf_acc(cv[j]);
        ov[j] = 1.0f - be * (1.0f - ct);   // exact ref expression order
    }
    reinterpret_cast<f32x4*>(ws)[idx] = ov;

    if (idx < C4) {
        const int TC = TC4 * 4;
        const f32x4 alv = reinterpret_cast<const f32x4*>(alpha)[c4];
        const f32x4 gav = reinterpret_cast<const f32x4*>(gamma_)[c4];
        const f32x4 tav = reinterpret_cast<const f32x4*>(tau  )[c4];
        const f32x4 vtv = reinterpret_cast<const f32x4*>(Vth  )[c4];
        const f32x4 lkv = reinterpret_cast<const f32x4*>(leak )[c4];
        const f32x4 rvv = reinterpret_cast<const f32x4*>(reVth)[c4];

        f32x4 decay, leakt, vth_s, rvc, ga;
        #pragma unroll
        for (int j = 0; j < 4; ++j) {
            float al = alv[j] > 0.0f ? 1.0f : 0.0f;
            float g  = gav[j] > 0.0f ? 1.0f : 0.0f;
            float tau_s   = sigmoidf_acc(tav[j]);
            float vth_sj  = sigmoidf_acc(vtv[j]);
            float leak_s  = sigmoidf_acc(lkv[j]);
            float reVth_s = sigmoidf_acc(rvv[j]);
            decay[j] = 1.0f - al * (1.0f - tau_s);
            leakt[j] = (1.0f - al) * leak_s;
            vth_s[j] = vth_sj;
            rvc[j]   = (1.0f - g) * reVth_s;
            ga[j]    = g;
        }
        f32x4* p = reinterpret_cast<f32x4*>(ws + TC);
        p[0 * C4 + c4] = decay;
        p[1 * C4 + c4] = leakt;
        p[2 * C4 + c4] = vth_s;
        p[3 * C4 + c4] = rvc;
        p[4 * C4 + c4] = ga;
    }
}

__global__ __launch_bounds__(256) void glif_fwd_kernel(
    const float* __restrict__ x,
    const float* __restrict__ ws,   // iscale [T*C] + params 5x[C]
    float* __restrict__ out,
    int BC4, int C4, int T)
{
#pragma clang fp contract(off)
    const int half = BC4 >> 1;
    int idx = blockIdx.x * blockDim.x + threadIdx.x;
    if (idx >= half) return;
    int c4 = idx & (C4 - 1);
    const int TC4 = T * C4;

    const f32x4* __restrict__ p = reinterpret_cast<const f32x4*>(ws) + TC4;
    const f32x4 decay = p[0 * C4 + c4];
    const f32x4 leakt = p[1 * C4 + c4];
    const f32x4 vth_s = p[2 * C4 + c4];
    const f32x4 rvc   = p[3 * C4 + c4];
    const f32x4 ga    = p[4 * C4 + c4];

    float ua[4] = {0.f,0.f,0.f,0.f}, oa[4] = {0.f,0.f,0.f,0.f};
    float ub[4] = {0.f,0.f,0.f,0.f}, ob[4] = {0.f,0.f,0.f,0.f};

    const f32x4* __restrict__ x4  = reinterpret_cast<const f32x4*>(x);
    const f32x4* __restrict__ is4 = reinterpret_cast<const f32x4*>(ws);
    f32x4* __restrict__ o4 = reinterpret_cast<f32x4*>(out);

    const size_t baseA = (size_t)idx;
    const size_t baseB = (size_t)idx + (size_t)half;
    const size_t strd  = (size_t)BC4;

    // depth-2 rolled pipeline on both x streams
    f32x4 xa0 = __builtin_nontemporal_load(&x4[baseA]);
    f32x4 xb0 = __builtin_nontemporal_load(&x4[baseB]);
    f32x4 xa1, xb1;
    if (T > 1) {
        xa1 = __builtin_nontemporal_load(&x4[baseA + strd]);
        xb1 = __builtin_nontemporal_load(&x4[baseB + strd]);
    }

    for (int t = 0; t < T; ++t) {
        f32x4 xa2, xb2;
        if (t + 2 < T) {
            xa2 = __builtin_nontemporal_load(&x4[baseA + (size_t)(t + 2) * strd]);
            xb2 = __builtin_nontemporal_load(&x4[baseB + (size_t)(t + 2) * strd]);
        }
        f32x4 iv = is4[(size_t)t * (size_t)C4 + (size_t)c4];  // L1/L2-hot

        f32x4 ova, ovb;
        #pragma unroll
        for (int j = 0; j < 4; ++j) {
            float Ia  = xa0[j] * iv[j];
            float una = decay[j] * ua[j] * (1.0f - ga[j] * oa[j]) - leakt[j] + Ia
                        - rvc[j] * oa[j];
            float ona = (una - vth_s[j] >= 0.0f) ? 1.0f : 0.0f;
            ua[j] = una; oa[j] = ona; ova[j] = ona;

            float Ib  = xb0[j] * iv[j];
            float unb = decay[j] * ub[j] * (1.0f - ga[j] * ob[j]) - leakt[j] + Ib
                        - rvc[j] * ob[j];
            float onb = (unb - vth_s[j] >= 0.0f) ? 1.0f : 0.0f;
            ub[j] = unb; ob[j] = onb; ovb[j] = onb;
        }

        o4[baseA + (size_t)t * strd] = ova;
        o4[baseB + (size_t)t * strd] = ovb;

        xa0 = xa1; xa1 = xa2;
        xb0 = xb1; xb1 = xb2;
    }
}

extern "C" void kernel_launch(void* const* d_in, const int* in_sizes, int n_in,
                              void* d_out, int out_size, void* d_ws, size_t ws_size,
                              hipStream_t stream) {
    const float* x       = (const float*)d_in[0];
    const float* tau     = (const float*)d_in[1];
    const float* Vth     = (const float*)d_in[2];
    const float* leak    = (const float*)d_in[3];
    const float* reVth   = (const float*)d_in[4];
    const float* conduct = (const float*)d_in[5];
    const float* alpha   = (const float*)d_in[6];
    const float* beta    = (const float*)d_in[7];
    const float* gamma_  = (const float*)d_in[8];
    float* out = (float*)d_out;

    const int C  = in_sizes[1];                        // 1024
    const int T  = in_sizes[5] / C;                    // 16
    const long long BC = (long long)in_sizes[0] / T;   // B*C
    const int BC4 = (int)(BC / 4);
    const int C4  = C / 4;
    const int TC4 = T * C4;
    const int half = BC4 / 2;

    const int block = 256;

    float* ws = (float*)d_ws;  // needs (T*C + 5*C)*4 = 84KB
    glif_prep_kernel<<<(TC4 + block - 1) / block, block, 0, stream>>>(
        conduct, beta, tau, Vth, leak, reVth, alpha, gamma_, ws, TC4, C4);
    glif_fwd_kernel<<<(half + block - 1) / block, block, 0, stream>>>(
        x, ws, out, BC4, C4, T);
}